// Round 6
// baseline (15087.962 us; speedup 1.0000x reference)
//
#include <hip/hip_runtime.h>
#include <hip/hip_bf16.h>

#define T_    256
#define B_    64
#define EMB_  300
#define HID_  256
#define G_    1024   // 4*HID
#define L_    20
#define M_    (T_*B_)  // 16384

typedef float f32x4 __attribute__((ext_vector_type(4)));

// ---------------------------------------------------------------------------
// Kernel 1: xp[dir][t*B+b][g] = dot(emb[sent[t,b]], Wih_dir[g,:]) + b_dir[g]
// ---------------------------------------------------------------------------
__global__ __launch_bounds__(256) void k_xproj(
    const float* __restrict__ emb,
    const float* __restrict__ Wih_f, const float* __restrict__ b_f,
    const float* __restrict__ Wih_b, const float* __restrict__ b_b,
    const int*   __restrict__ sent,
    float* __restrict__ xp)
{
    __shared__ float As[16][68];
    __shared__ float Bs[16][68];
    __shared__ int   words[64];

    const int tid = threadIdx.x;
    const int n0  = blockIdx.x * 64;
    const int m0  = blockIdx.y * 64;
    const int dir = n0 >> 10;
    const int g0  = n0 & 1023;
    const float* __restrict__ Wih  = dir ? Wih_b : Wih_f;
    const float* __restrict__ bias = dir ? b_b   : b_f;

    if (tid < 64) words[tid] = sent[m0 + tid];
    __syncthreads();

    const int r = tid >> 2;
    const int q = tid & 3;
    const float* aptr = emb + (size_t)words[r] * EMB_ + q * 4;
    const float* bptr = Wih + (size_t)(g0 + r) * EMB_ + q * 4;

    const int tx = tid & 15;
    const int ty = tid >> 4;
    float acc[4][4] = {};

    for (int k0 = 0; k0 < 304; k0 += 16) {
        const int k = k0 + q * 4;
        float4 av = make_float4(0.f, 0.f, 0.f, 0.f);
        float4 bv = make_float4(0.f, 0.f, 0.f, 0.f);
        if (k < 300) {
            av = *(const float4*)(aptr + k0);
            bv = *(const float4*)(bptr + k0);
        }
        As[q*4+0][r] = av.x; As[q*4+1][r] = av.y; As[q*4+2][r] = av.z; As[q*4+3][r] = av.w;
        Bs[q*4+0][r] = bv.x; Bs[q*4+1][r] = bv.y; Bs[q*4+2][r] = bv.z; Bs[q*4+3][r] = bv.w;
        __syncthreads();
        #pragma unroll
        for (int kk = 0; kk < 16; ++kk) {
            const float4 a = *(const float4*)&As[kk][ty * 4];
            const float4 b = *(const float4*)&Bs[kk][tx * 4];
            acc[0][0] += a.x*b.x; acc[0][1] += a.x*b.y; acc[0][2] += a.x*b.z; acc[0][3] += a.x*b.w;
            acc[1][0] += a.y*b.x; acc[1][1] += a.y*b.y; acc[1][2] += a.y*b.z; acc[1][3] += a.y*b.w;
            acc[2][0] += a.z*b.x; acc[2][1] += a.z*b.y; acc[2][2] += a.z*b.z; acc[2][3] += a.z*b.w;
            acc[3][0] += a.w*b.x; acc[3][1] += a.w*b.y; acc[3][2] += a.w*b.z; acc[3][3] += a.w*b.w;
        }
        __syncthreads();
    }

    float* out = xp + (size_t)dir * M_ * G_;
    const int g = g0 + tx * 4;
    const float4 bs4 = *(const float4*)(bias + g);
    #pragma unroll
    for (int im = 0; im < 4; ++im) {
        const int m = m0 + ty * 4 + im;
        float4 rv;
        rv.x = acc[im][0] + bs4.x;
        rv.y = acc[im][1] + bs4.y;
        rv.z = acc[im][2] + bs4.z;
        rv.w = acc[im][3] + bs4.w;
        *(float4*)(out + (size_t)m * G_ + g) = rv;
    }
}

// ---------------------------------------------------------------------------
// Kernel 2 (R5 redesign): EXCHANGE-FREE bidirectional LSTM scan.
// 128 blocks x 1024 threads; block = (dir, batch). The ENTIRE Whh (1 MB)
// lives in this block's VGPRs: thread (wave w, u=16w+lane%16, kq=lane/16)
// holds 4 gate rows x 64 k = 256 VGPRs. h state never leaves the block:
// LDS double-buffer, ONE __syncthreads per step, no atomics, no polling,
// plain (non-cooperative) launch. VALU floor: 2048 cyc/SIMD/step.
// kq=0 threads own cell state c[u] in registers and do the epilogue.
// ---------------------------------------------------------------------------
__global__ __launch_bounds__(1024, 1) void k_lstm_scan(
    const float* __restrict__ Whh_f, const float* __restrict__ Whh_b,
    const float* __restrict__ xp, float* __restrict__ hbuf)
{
    const int blk  = blockIdx.x;
    const int dir  = blk >> 6;
    const int b    = blk & 63;
    const int tid  = threadIdx.x;
    const int w    = tid >> 6;          // wave 0..15
    const int lane = tid & 63;
    const int ul   = lane & 15;
    const int kq   = lane >> 4;         // 0..3 (64 k each)
    const int u    = w * 16 + ul;       // hidden unit 0..255

    const float* __restrict__ Whh = dir ? Whh_b : Whh_f;
    float* __restrict__ hdir = hbuf + (size_t)dir * M_ * HID_;

    // h double-buffer; kq-slices at stride 68 words -> broadcast reads hit
    // 16 distinct banks per instruction (conflict-free)
    __shared__ float hs[2][280];

    // whole-Whh register slice: wv[g][i] = Whh[g*256+u][kq*64+4i .. +4]
    f32x4 wv[4][16];
    {
        #pragma unroll
        for (int g = 0; g < 4; ++g) {
            const f32x4* wrow = (const f32x4*)(Whh + ((size_t)g * HID_ + u) * HID_ + kq * 64);
            #pragma unroll
            for (int i = 0; i < 16; ++i) wv[g][i] = wrow[i];
        }
    }

    if (tid < 280) hs[0][tid] = 0.f;
    float c = 0.f;                      // cell state (kq==0 threads)
    __syncthreads();

    int p = 0;
    for (int t = 0; t < T_; ++t) {
        const int t_eff = dir ? (T_ - 1 - t) : t;

        // pin the 256 weight VGPRs live at loop top (loads cannot sink)
        #pragma unroll
        for (int g = 0; g < 4; ++g)
            #pragma unroll
            for (int i = 0; i < 16; ++i) asm volatile("" : "+v"(wv[g][i]));

        // xp gate biases for this (t,b,u) — issued early, hidden under MAC
        float x0 = 0.f, x1 = 0.f, x2 = 0.f, x3 = 0.f;
        if (kq == 0) {
            const float* xr = xp + ((size_t)dir * M_ + (size_t)t_eff * B_ + b) * G_ + u;
            x0 = xr[0]; x1 = xr[HID_]; x2 = xr[2 * HID_]; x3 = xr[3 * HID_];
        }

        // gate MAC: a_g = sum_k Whh[g*256+u][k] * h[k]  (this thread: 64-k slice)
        float a0 = 0.f, a1 = 0.f, a2 = 0.f, a3 = 0.f;
        {
            const f32x4* hv = (const f32x4*)&hs[p][kq * 68];
            #pragma unroll
            for (int i = 0; i < 16; ++i) {
                const f32x4 h4 = hv[i];
                a0 += wv[0][i].x*h4.x + wv[0][i].y*h4.y + wv[0][i].z*h4.z + wv[0][i].w*h4.w;
                a1 += wv[1][i].x*h4.x + wv[1][i].y*h4.y + wv[1][i].z*h4.z + wv[1][i].w*h4.w;
                a2 += wv[2][i].x*h4.x + wv[2][i].y*h4.y + wv[2][i].z*h4.z + wv[2][i].w*h4.w;
                a3 += wv[3][i].x*h4.x + wv[3][i].y*h4.y + wv[3][i].z*h4.z + wv[3][i].w*h4.w;
            }
        }
        // k-reduce across the 4 kq groups (lanes 16,32 apart)
        a0 += __shfl_xor(a0, 16); a0 += __shfl_xor(a0, 32);
        a1 += __shfl_xor(a1, 16); a1 += __shfl_xor(a1, 32);
        a2 += __shfl_xor(a2, 16); a2 += __shfl_xor(a2, 32);
        a3 += __shfl_xor(a3, 16); a3 += __shfl_xor(a3, 32);

        if (kq == 0) {
            const float gi = a0 + x0;
            const float gf = a1 + x1;
            const float gg = a2 + x2;
            const float go = a3 + x3;
            const float i_ = 1.f / (1.f + __expf(-gi));
            const float f_ = 1.f / (1.f + __expf(-gf));
            const float g_ = tanhf(gg);
            const float o_ = 1.f / (1.f + __expf(-go));
            c = f_ * c + i_ * g_;
            const float hn = o_ * tanhf(c);
            hs[1 - p][(u >> 6) * 68 + (u & 63)] = hn;                 // next-step h
            hdir[((size_t)t_eff * B_ + b) * HID_ + u] = hn;           // history
        }
        __syncthreads();
        p ^= 1;
    }
}

// ---------------------------------------------------------------------------
// Kernel 3: emissions[t,b,l] = b_top[l] + h_f . W_top[l,:256] + h_b . W_top[l,256:]
// ---------------------------------------------------------------------------
__global__ __launch_bounds__(256) void k_emis(
    const float* __restrict__ Wt, const float* __restrict__ bt,
    const float* __restrict__ hbuf, float* __restrict__ em)
{
    const int gid = blockIdx.x * 256 + threadIdx.x;
    if (gid >= M_ * L_) return;
    const int m = gid / L_;
    const int l = gid - m * L_;
    const float4* hf  = (const float4*)(hbuf + (size_t)m * HID_);
    const float4* hbk = (const float4*)(hbuf + (size_t)M_ * HID_ + (size_t)m * HID_);
    const float4* w0  = (const float4*)(Wt + (size_t)l * 2 * HID_);
    const float4* w1  = w0 + HID_ / 4;
    float acc = bt[l];
    #pragma unroll 4
    for (int k = 0; k < HID_ / 4; ++k) {
        float4 h = hf[k],  w = w0[k];
        acc += h.x*w.x + h.y*w.y + h.z*w.z + h.w*w.w;
        h = hbk[k]; w = w1[k];
        acc += h.x*w.x + h.y*w.y + h.z*w.z + h.w*w.w;
    }
    em[gid] = acc;
}

// ---------------------------------------------------------------------------
// Kernel 4: CRF per-sequence forward + gold score. One block per b.
// ---------------------------------------------------------------------------
__global__ __launch_bounds__(64) void k_crf(
    const float* __restrict__ start_t, const float* __restrict__ end_t,
    const float* __restrict__ trans,
    const int* __restrict__ sent, const int* __restrict__ labels,
    const float* __restrict__ em, float* __restrict__ res)
{
    const int b = blockIdx.x;
    const int tid = threadIdx.x;
    __shared__ float tr[L_ * L_];
    __shared__ float alpha[2][L_];
    __shared__ float red[64];
    __shared__ int   redi[64];
    __shared__ float sdenom;

    for (int i = tid; i < L_ * L_; i += 64) tr[i] = trans[i];
    if (tid < L_) alpha[0][tid] = start_t[tid] + em[b * L_ + tid];
    __syncthreads();

    float pre_em = (tid < L_) ? em[(B_ + b) * L_ + tid] : 0.f;
    int   pre_m  = sent[B_ + b];

    int p = 0;
    for (int t = 1; t < T_; ++t) {
        const float emt = pre_em;
        const int   mt  = pre_m;
        if (t + 1 < T_) {
            if (tid < L_) pre_em = em[((t + 1) * B_ + b) * L_ + tid];
            pre_m = sent[(t + 1) * B_ + b];
        }
        float val = 0.f;
        if (tid < L_) {
            if (mt != 0) {
                float mx = -1e30f;
                #pragma unroll
                for (int i = 0; i < L_; ++i) mx = fmaxf(mx, alpha[p][i] + tr[i * L_ + tid]);
                float s = 0.f;
                #pragma unroll
                for (int i = 0; i < L_; ++i) s += __expf(alpha[p][i] + tr[i * L_ + tid] - mx);
                val = mx + __logf(s) + emt;
            } else {
                val = alpha[p][tid];
            }
        }
        if (tid < L_) alpha[1 - p][tid] = val;
        __syncthreads();
        p ^= 1;
    }

    if (tid == 0) {
        float mx = -1e30f;
        for (int j = 0; j < L_; ++j) mx = fmaxf(mx, alpha[p][j] + end_t[j]);
        float s = 0.f;
        for (int j = 0; j < L_; ++j) s += __expf(alpha[p][j] + end_t[j] - mx);
        sdenom = mx + __logf(s);
    }

    float loc = 0.f;
    int   cnt = 0;
    for (int t = tid; t < T_; t += 64) {
        const int masked = (sent[t * B_ + b] != 0);
        cnt += masked;
        if (t >= 1 && masked) {
            const int tp = labels[(t - 1) * B_ + b];
            const int tc = labels[t * B_ + b];
            loc += tr[tp * L_ + tc] + em[(t * B_ + b) * L_ + tc];
        }
    }
    red[tid] = loc; redi[tid] = cnt;
    __syncthreads();
    if (tid == 0) {
        float s = 0.f; int c = 0;
        for (int i = 0; i < 64; ++i) { s += red[i]; c += redi[i]; }
        const int tag0 = labels[b];
        const int seq_end = c - 1;
        const int last = labels[seq_end * B_ + b];
        const float score = start_t[tag0] + em[b * L_ + tag0] + s + end_t[last];
        res[b] = score - sdenom;
    }
}

// ---------------------------------------------------------------------------
// Kernel 5: out[0] = -sum_b res[b]
// ---------------------------------------------------------------------------
__global__ __launch_bounds__(64) void k_final(const float* __restrict__ res,
                                              float* __restrict__ out)
{
    __shared__ float red[64];
    red[threadIdx.x] = res[threadIdx.x];
    __syncthreads();
    if (threadIdx.x == 0) {
        float s = 0.f;
        for (int i = 0; i < 64; ++i) s += red[i];
        out[0] = -s;
    }
}

// ---------------------------------------------------------------------------
extern "C" void kernel_launch(void* const* d_in, const int* in_sizes, int n_in,
                              void* d_out, int out_size, void* d_ws, size_t ws_size,
                              hipStream_t stream)
{
    const float* emb     = (const float*)d_in[0];
    const float* Wih_f   = (const float*)d_in[1];
    const float* Whh_f   = (const float*)d_in[2];
    const float* b_f     = (const float*)d_in[3];
    const float* Wih_b   = (const float*)d_in[4];
    const float* Whh_b   = (const float*)d_in[5];
    const float* b_b     = (const float*)d_in[6];
    const float* W_top   = (const float*)d_in[7];
    const float* b_top   = (const float*)d_in[8];
    const float* start_t = (const float*)d_in[9];
    const float* end_t   = (const float*)d_in[10];
    const float* trans   = (const float*)d_in[11];
    const int*   sent    = (const int*)d_in[12];
    const int*   labels  = (const int*)d_in[13];
    float* out = (float*)d_out;

    float* wsf  = (float*)d_ws;
    float* xp   = wsf;                                   // 2*M*G floats
    float* hbuf = xp   + (size_t)2 * M_ * G_;            // 2*M*H
    float* em   = hbuf + (size_t)2 * M_ * HID_;          // M*L
    float* res  = em   + (size_t)M_ * L_;                // B

    // 1) input projection GEMM (both dirs)
    k_xproj<<<dim3(2048 / 64, M_ / 64), 256, 0, stream>>>(
        emb, Wih_f, b_f, Wih_b, b_b, sent, xp);

    // 2) exchange-free bidirectional scan: 128 independent blocks
    k_lstm_scan<<<128, 1024, 0, stream>>>(Whh_f, Whh_b, xp, hbuf);

    // 3) emissions
    k_emis<<<(M_ * L_ + 255) / 256, 256, 0, stream>>>(W_top, b_top, hbuf, em);

    // 4) CRF per-sequence
    k_crf<<<B_, 64, 0, stream>>>(start_t, end_t, trans, sent, labels, em, res);

    // 5) final sum
    k_final<<<1, 64, 0, stream>>>(res, out);
}